// Round 1
// baseline (358.173 us; speedup 1.0000x reference)
//
#include <hip/hip_runtime.h>
#include <math.h>

#define L       512
#define BLK     256
#define KTOP    32
#define NEGV    (-1e30f)
#define MARGINF 0.5f

// jax.nn.softplus(x) = logaddexp(x, 0) = max(x,0) + log1p(exp(-|x|))
__device__ __forceinline__ float softplus_f(float x) {
    return fmaxf(x, 0.0f) + log1pf(expf(-fabsf(x)));
}

// Block-wide reduction over 256 threads (4 waves of 64).
// red must be >= 4 floats of shared memory. Includes trailing sync so red
// can be reused immediately after return.
__device__ __forceinline__ float blockReduceMax(float v, float* red) {
    const int lane = threadIdx.x & 63;
    const int wid  = threadIdx.x >> 6;
#pragma unroll
    for (int off = 32; off; off >>= 1)
        v = fmaxf(v, __shfl_down(v, off, 64));
    if (lane == 0) red[wid] = v;
    __syncthreads();
    float r = fmaxf(fmaxf(red[0], red[1]), fmaxf(red[2], red[3]));
    __syncthreads();
    return r;
}

__device__ __forceinline__ float blockReduceSum(float v, float* red) {
    const int lane = threadIdx.x & 63;
    const int wid  = threadIdx.x >> 6;
#pragma unroll
    for (int off = 32; off; off >>= 1)
        v += __shfl_down(v, off, 64);
    if (lane == 0) red[wid] = v;
    __syncthreads();
    float r = (red[0] + red[1]) + (red[2] + red[3]);
    __syncthreads();
    return r;
}

__global__ __launch_bounds__(BLK) void graph_loss_kernel(
    const float* __restrict__ logits,
    const float* __restrict__ targets,
    float* __restrict__ acc /* [4]: sum_listwise, n_haspos, sum_pair, n_active */)
{
    __shared__ float sv[L];
    __shared__ float red[4];

    const int g = blockIdx.x;
    const int t = threadIdx.x;
    const float* lg = logits  + (size_t)g * L;
    const float* tg = targets + (size_t)g * L;

    // Each thread owns elements t and t+256 (coalesced).
    const float l0 = lg[t];
    const float l1 = lg[t + BLK];
    const bool  p0 = tg[t]       > 0.5f;
    const bool  p1 = tg[t + BLK] > 0.5f;
    const float s0 = l0 * 10.0f;  // logits / TEMPERATURE, T = 0.1
    const float s1 = l1 * 10.0f;

    // ---- listwise: log_denom over all, log_num over positives ----
    const float m_all = blockReduceMax(fmaxf(s0, s1), red);
    const float sum_all = blockReduceSum(expf(s0 - m_all) + expf(s1 - m_all), red);

    const float m_pos = blockReduceMax(fmaxf(p0 ? s0 : NEGV, p1 ? s1 : NEGV), red);
    const float pos_cnt = blockReduceSum((p0 ? 1.0f : 0.0f) + (p1 ? 1.0f : 0.0f), red);
    const bool has_pos = pos_cnt > 0.0f;
    const float sum_pos = blockReduceSum((p0 ? expf(s0 - m_pos) : 0.0f) +
                                         (p1 ? expf(s1 - m_pos) : 0.0f), red);

    // ---- pairwise: exact top-32 of negatives via bitonic sort in LDS ----
    sv[t]       = p0 ? NEGV : l0;
    sv[t + BLK] = p1 ? NEGV : l1;
    __syncthreads();

    for (int k = 2; k <= L; k <<= 1) {
        for (int j = k >> 1; j > 0; j >>= 1) {
#pragma unroll
            for (int w = 0; w < 2; ++w) {
                const int i   = t + w * BLK;
                const int ixj = i ^ j;
                if (ixj > i) {  // each disjoint pair handled by exactly one thread
                    const bool desc = ((i & k) == 0);
                    const float a = sv[i], b = sv[ixj];
                    if (desc ? (a < b) : (a > b)) { sv[i] = b; sv[ixj] = a; }
                }
            }
            __syncthreads();
        }
    }
    // sv[0..31] now hold the top-32 negative logits (descending).

    const int neg_cnt = L - (int)pos_cnt;
    const int kg = neg_cnt < KTOP ? neg_cnt : KTOP;

    float psum = 0.0f;
    if (p0) {
        for (int n = 0; n < kg; ++n) psum += softplus_f(MARGINF + sv[n] - l0);
    }
    if (p1) {
        for (int n = 0; n < kg; ++n) psum += softplus_f(MARGINF + sv[n] - l1);
    }
    __syncthreads();
    const float psum_total = blockReduceSum(psum, red);

    if (t == 0) {
        const float log_denom = m_all + logf(sum_all);
        float lw = 0.0f;
        if (has_pos) {
            const float log_num = m_pos + logf(sum_pos);
            lw = log_denom - log_num;  // -(log_num - log_denom)
        }
        atomicAdd(&acc[0], lw);
        atomicAdd(&acc[1], has_pos ? 1.0f : 0.0f);

        const bool active = has_pos && (kg > 0);
        float contrib = 0.0f;
        if (active) contrib = psum_total / fmaxf(pos_cnt * (float)kg, 1.0f);
        atomicAdd(&acc[2], contrib);
        atomicAdd(&acc[3], active ? 1.0f : 0.0f);
    }
}

__global__ void finalize_kernel(const float* __restrict__ acc,
                                float* __restrict__ out)
{
    const float listwise = acc[0] / fmaxf(acc[1], 1.0f);
    const float pairwise = acc[2] / fmaxf(acc[3], 1.0f);
    out[0] = 1.0f * listwise + 0.5f * pairwise;
}

extern "C" void kernel_launch(void* const* d_in, const int* in_sizes, int n_in,
                              void* d_out, int out_size, void* d_ws, size_t ws_size,
                              hipStream_t stream) {
    const float* logits  = (const float*)d_in[0];
    const float* targets = (const float*)d_in[1];
    // d_in[2] (edge_batch) and d_in[3] (num_graphs) are implied by layout:
    // segments are contiguous, equal-size L=512.
    const int E = in_sizes[0];
    const int G = E / L;

    float* acc = (float*)d_ws;
    hipMemsetAsync(acc, 0, 4 * sizeof(float), stream);
    graph_loss_kernel<<<G, BLK, 0, stream>>>(logits, targets, acc);
    finalize_kernel<<<1, 1, 0, stream>>>(acc, (float*)d_out);
}

// Round 2
// 142.808 us; speedup vs baseline: 2.5081x; 2.5081x over previous
//
#include <hip/hip_runtime.h>
#include <math.h>

#define L        512
#define BLK      256
#define WPB      4          // waves (graphs) per block
#define KTOP     32
#define NEGV     (-1e30f)
#define MARGINF  0.5f

// jax.nn.softplus(x) = max(x,0) + log1p(exp(-|x|))
__device__ __forceinline__ float softplus_f(float x) {
    return fmaxf(x, 0.0f) + log1pf(expf(-fabsf(x)));
}

__device__ __forceinline__ float waveMax(float v) {
#pragma unroll
    for (int off = 32; off; off >>= 1)
        v = fmaxf(v, __shfl_xor(v, off, 64));
    return v;
}

__device__ __forceinline__ float waveSum(float v) {
#pragma unroll
    for (int off = 32; off; off >>= 1)
        v += __shfl_xor(v, off, 64);
    return v;
}

__global__ __launch_bounds__(BLK) void graph_loss_kernel(
    const float* __restrict__ logits,
    const float* __restrict__ targets,
    int G,
    float* __restrict__ acc /* [4]: sum_listwise, n_haspos, sum_pair, n_active */)
{
    __shared__ float hard_s[WPB][KTOP];
    __shared__ float pos_s[WPB][L];
    __shared__ float blk_acc[4];

    const int tid  = threadIdx.x;
    const int lane = tid & 63;
    const int w    = tid >> 6;
    const int g    = blockIdx.x * WPB + w;

    if (tid < 4) blk_acc[tid] = 0.0f;
    __syncthreads();

    if (g < G) {
        // Each lane owns elements [lane*8, lane*8+8): two float4 loads each.
        const float4* lg4 = (const float4*)(logits  + (size_t)g * L);
        const float4* tg4 = (const float4*)(targets + (size_t)g * L);
        const float4 la = lg4[lane * 2], lb = lg4[lane * 2 + 1];
        const float4 ta = tg4[lane * 2], tb = tg4[lane * 2 + 1];
        float v[8]  = {la.x, la.y, la.z, la.w, lb.x, lb.y, lb.z, lb.w};
        float tv[8] = {ta.x, ta.y, ta.z, ta.w, tb.x, tb.y, tb.z, tb.w};
        bool  p[8];

        // ---- listwise LSEs (scaled by 1/T = 10) ----
        float s_mx = NEGV, p_mx = NEGV;
        int   pcnt = 0;
#pragma unroll
        for (int e = 0; e < 8; e++) {
            p[e] = tv[e] > 0.5f;
            const float sc = v[e] * 10.0f;
            s_mx = fmaxf(s_mx, sc);
            if (p[e]) { p_mx = fmaxf(p_mx, sc); pcnt++; }
        }
        const float m_all = waveMax(s_mx);
        const float m_pos = waveMax(p_mx);
        float se_all = 0.0f, se_pos = 0.0f;
#pragma unroll
        for (int e = 0; e < 8; e++) {
            const float sc = v[e] * 10.0f;
            se_all += expf(sc - m_all);
            se_pos += p[e] ? expf(sc - m_pos) : 0.0f;
        }
        const float sum_all = waveSum(se_all);
        const float sum_pos = waveSum(se_pos);
        const int   P       = (int)waveSum((float)pcnt);
        const int   neg_cnt = L - P;
        const int   kg      = neg_cnt < KTOP ? neg_cnt : KTOP;

        // ---- top-32 negatives: per-lane descending sort, then 32-round
        //      tournament (wave-max of heads, pop the winner's head) ----
        float nv[8];
#pragma unroll
        for (int e = 0; e < 8; e++) nv[e] = p[e] ? NEGV : v[e];
#pragma unroll
        for (int i = 0; i < 7; i++)
#pragma unroll
            for (int j = 0; j < 7 - i; j++) {
                const float hi = fmaxf(nv[j], nv[j + 1]);
                const float lo = fminf(nv[j], nv[j + 1]);
                nv[j] = hi; nv[j + 1] = lo;
            }

        for (int r = 0; r < KTOP; r++) {
            const float m = waveMax(nv[0]);
            const unsigned long long b = __ballot(nv[0] == m);
            const int src = __ffsll(b) - 1;
            if (lane == src) {
#pragma unroll
                for (int e = 0; e < 7; e++) nv[e] = nv[e + 1];
                nv[7] = NEGV;
            }
            if (lane == 0) hard_s[w][r] = m;
        }

        // ---- compact positive logits into LDS via wave prefix scan ----
        int scan = pcnt;
#pragma unroll
        for (int off = 1; off < 64; off <<= 1) {
            const int y = __shfl_up(scan, off, 64);
            if (lane >= off) scan += y;
        }
        int idx = scan - pcnt;  // exclusive prefix
#pragma unroll
        for (int e = 0; e < 8; e++) {
            if (p[e]) pos_s[w][idx++] = v[e];
        }

        // ---- dense pairwise loop over P x KTOP ----
        float psum = 0.0f;
        const int npairs = P * KTOP;
        for (int pi = lane; pi < npairs; pi += 64) {
            const int n  = pi & (KTOP - 1);
            const int pp = pi >> 5;
            if (n < kg)
                psum += softplus_f(MARGINF + hard_s[w][n] - pos_s[w][pp]);
        }
        psum = waveSum(psum);

        if (lane == 0) {
            const bool has_pos = P > 0;
            float lw = 0.0f;
            if (has_pos)
                lw = (m_all + logf(sum_all)) - (m_pos + logf(sum_pos));
            atomicAdd(&blk_acc[0], lw);
            atomicAdd(&blk_acc[1], has_pos ? 1.0f : 0.0f);
            const bool active = has_pos && (kg > 0);
            const float contrib =
                active ? psum / fmaxf((float)P * (float)kg, 1.0f) : 0.0f;
            atomicAdd(&blk_acc[2], contrib);
            atomicAdd(&blk_acc[3], active ? 1.0f : 0.0f);
        }
    }

    __syncthreads();
    if (tid == 0) {
        atomicAdd(&acc[0], blk_acc[0]);
        atomicAdd(&acc[1], blk_acc[1]);
        atomicAdd(&acc[2], blk_acc[2]);
        atomicAdd(&acc[3], blk_acc[3]);
    }
}

__global__ void finalize_kernel(const float* __restrict__ acc,
                                float* __restrict__ out)
{
    const float listwise = acc[0] / fmaxf(acc[1], 1.0f);
    const float pairwise = acc[2] / fmaxf(acc[3], 1.0f);
    out[0] = 1.0f * listwise + 0.5f * pairwise;
}

extern "C" void kernel_launch(void* const* d_in, const int* in_sizes, int n_in,
                              void* d_out, int out_size, void* d_ws, size_t ws_size,
                              hipStream_t stream) {
    const float* logits  = (const float*)d_in[0];
    const float* targets = (const float*)d_in[1];
    // d_in[2]/d_in[3]: segments are contiguous, equal-size L=512 by construction.
    const int E = in_sizes[0];
    const int G = E / L;

    float* acc = (float*)d_ws;
    hipMemsetAsync(acc, 0, 4 * sizeof(float), stream);
    graph_loss_kernel<<<(G + WPB - 1) / WPB, BLK, 0, stream>>>(logits, targets, G, acc);
    finalize_kernel<<<1, 1, 0, stream>>>(acc, (float*)d_out);
}

// Round 3
// 122.596 us; speedup vs baseline: 2.9216x; 1.1649x over previous
//
#include <hip/hip_runtime.h>
#include <math.h>

#define L        512
#define BLK      256
#define WPB      4          // waves (graphs) per block
#define KTOP     32
#define NEGV     (-1e30f)
#define MARGINF  0.5f

// jax.nn.softplus(x) = max(x,0) + log1p(exp(-|x|))
__device__ __forceinline__ float softplus_f(float x) {
    return fmaxf(x, 0.0f) + log1pf(expf(-fabsf(x)));
}

__device__ __forceinline__ float waveSum(float v) {
#pragma unroll
    for (int off = 32; off; off >>= 1)
        v += __shfl_xor(v, off, 64);
    return v;
}

// # of set bits in m strictly below this lane
__device__ __forceinline__ unsigned lanes_below(unsigned long long m) {
    return __builtin_amdgcn_mbcnt_hi((unsigned)(m >> 32),
           __builtin_amdgcn_mbcnt_lo((unsigned)(m & 0xffffffffull), 0u));
}

__global__ __launch_bounds__(BLK) void graph_loss_kernel(
    const float* __restrict__ logits,
    const float* __restrict__ targets,
    int G,
    float* __restrict__ partials /* [gridDim.x*4] */)
{
    __shared__ float hard_s[WPB][KTOP];
    __shared__ float pos_s[WPB][L];
    __shared__ float wres[WPB][4];

    const int tid  = threadIdx.x;
    const int lane = tid & 63;
    const int w    = tid >> 6;
    const int g    = blockIdx.x * WPB + w;
    const bool valid = (g < G);   // wave-uniform

    float lw = 0.0f, contrib = 0.0f;
    float has_pos_f = 0.0f, active_f = 0.0f;
    int   P = 0, K = 0, c_gt = 0;
    float tval = 0.0f;
    bool  do_pair = false;

    if (valid) {
        // Each lane owns elements [lane*8, lane*8+8): two float4 loads each.
        const float4* lg4 = (const float4*)(logits  + (size_t)g * L);
        const float4* tg4 = (const float4*)(targets + (size_t)g * L);
        const float4 la = lg4[lane * 2], lb = lg4[lane * 2 + 1];
        const float4 ta = tg4[lane * 2], tb = tg4[lane * 2 + 1];
        float v[8]  = {la.x, la.y, la.z, la.w, lb.x, lb.y, lb.z, lb.w};
        float tv[8] = {ta.x, ta.y, ta.z, ta.w, tb.x, tb.y, tb.z, tb.w};
        bool  p[8];
        unsigned nu[8];  // order-preserving uint key of negatives; 0 for positives

#pragma unroll
        for (int e = 0; e < 8; e++) {
            p[e] = tv[e] > 0.5f;
            const unsigned i = __float_as_uint(v[e]);
            const unsigned msk = (unsigned)((int)i >> 31) | 0x80000000u;
            nu[e] = p[e] ? 0u : (i ^ msk);
        }

        // ---- listwise LSEs (scaled by 1/T = 10), batched butterflies ----
        float s_mx = NEGV, p_mx = NEGV;
#pragma unroll
        for (int e = 0; e < 8; e++) {
            const float sc = v[e] * 10.0f;
            s_mx = fmaxf(s_mx, sc);
            p_mx = fmaxf(p_mx, p[e] ? sc : NEGV);
        }
#pragma unroll
        for (int off = 32; off; off >>= 1) {
            s_mx = fmaxf(s_mx, __shfl_xor(s_mx, off, 64));
            p_mx = fmaxf(p_mx, __shfl_xor(p_mx, off, 64));
        }
        float se_all = 0.0f, se_pos = 0.0f;
#pragma unroll
        for (int e = 0; e < 8; e++) {
            const float sc = v[e] * 10.0f;
            se_all += expf(sc - s_mx);
            se_pos += expf(p[e] ? (sc - p_mx) : NEGV);  // exp(-1e30)=0
        }
#pragma unroll
        for (int off = 32; off; off >>= 1) {
            se_all += __shfl_xor(se_all, off, 64);
            se_pos += __shfl_xor(se_pos, off, 64);
        }

        // ---- compact positive logits into LDS (ballot + mbcnt), get P ----
        int pbase = 0;
#pragma unroll
        for (int e = 0; e < 8; e++) {
            const unsigned long long m = __ballot((int)p[e]);
            if (p[e]) pos_s[w][pbase + lanes_below(m)] = v[e];
            pbase += __popcll(m);
        }
        P = pbase;

        if (P > 0) {
            has_pos_f = 1.0f;
            lw = (s_mx + logf(se_all)) - (p_mx + logf(se_pos));
        }
        const int neg_cnt = L - P;
        K = neg_cnt < KTOP ? neg_cnt : KTOP;
        do_pair = (P > 0) && (K > 0);

        if (do_pair) {
            // ---- radix-select: T = key of K-th largest negative ----
            unsigned prefix = 0u;
            for (int b = 31; b >= 0; --b) {
                const unsigned cand = prefix | (1u << b);
                int cnt = 0;
#pragma unroll
                for (int e = 0; e < 8; e++)
                    cnt += __popcll(__ballot(nu[e] >= cand));
                if (cnt >= K) prefix = cand;
            }
            // recover float value of T
            const unsigned ti = prefix ^ ((prefix & 0x80000000u) ? 0x80000000u
                                                                 : 0xFFFFFFFFu);
            tval = __uint_as_float(ti);

            // ---- compact strict-greater hard negatives, get c_gt (<K) ----
            int hbase = 0;
#pragma unroll
            for (int e = 0; e < 8; e++) {
                const bool gt = nu[e] > prefix;
                const unsigned long long m = __ballot((int)gt);
                if (gt) hard_s[w][hbase + lanes_below(m)] = v[e];
                hbase += __popcll(m);
            }
            c_gt = hbase;
            active_f = 1.0f;
        }
    }

    __syncthreads();  // compaction visible (and wres slot reuse safety)

    if (do_pair) {
        float psum = 0.0f;
        for (int n = 0; n < c_gt; n++) {
            const float c = MARGINF + hard_s[w][n];
            for (int pp = lane; pp < P; pp += 64)
                psum += softplus_f(c - pos_s[w][pp]);
        }
        {   // (K - c_gt) tied copies of the threshold value, folded
            const float c  = MARGINF + tval;
            const float wt = (float)(K - c_gt);
            for (int pp = lane; pp < P; pp += 64)
                psum += wt * softplus_f(c - pos_s[w][pp]);
        }
        psum = waveSum(psum);
        contrib = psum / fmaxf((float)P * (float)K, 1.0f);
    }

    if (lane == 0) {
        wres[w][0] = lw;
        wres[w][1] = has_pos_f;
        wres[w][2] = contrib;
        wres[w][3] = active_f;
    }
    __syncthreads();
    if (tid < 4) {
        partials[blockIdx.x * 4 + tid] =
            wres[0][tid] + wres[1][tid] + wres[2][tid] + wres[3][tid];
    }
}

__global__ __launch_bounds__(BLK) void finalize_kernel(
    const float* __restrict__ partials, int nblocks, float* __restrict__ out)
{
    float s0 = 0, s1 = 0, s2 = 0, s3 = 0;
    for (int i = threadIdx.x; i < nblocks; i += BLK) {
        const float4 p = ((const float4*)partials)[i];
        s0 += p.x; s1 += p.y; s2 += p.z; s3 += p.w;
    }
#pragma unroll
    for (int off = 32; off; off >>= 1) {
        s0 += __shfl_xor(s0, off, 64);
        s1 += __shfl_xor(s1, off, 64);
        s2 += __shfl_xor(s2, off, 64);
        s3 += __shfl_xor(s3, off, 64);
    }
    __shared__ float red[4][4];
    const int lane = threadIdx.x & 63, wid = threadIdx.x >> 6;
    if (lane == 0) { red[wid][0]=s0; red[wid][1]=s1; red[wid][2]=s2; red[wid][3]=s3; }
    __syncthreads();
    if (threadIdx.x == 0) {
        const float a0 = red[0][0]+red[1][0]+red[2][0]+red[3][0];
        const float a1 = red[0][1]+red[1][1]+red[2][1]+red[3][1];
        const float a2 = red[0][2]+red[1][2]+red[2][2]+red[3][2];
        const float a3 = red[0][3]+red[1][3]+red[2][3]+red[3][3];
        const float listwise = a0 / fmaxf(a1, 1.0f);
        const float pairwise = a2 / fmaxf(a3, 1.0f);
        out[0] = 1.0f * listwise + 0.5f * pairwise;
    }
}

extern "C" void kernel_launch(void* const* d_in, const int* in_sizes, int n_in,
                              void* d_out, int out_size, void* d_ws, size_t ws_size,
                              hipStream_t stream) {
    const float* logits  = (const float*)d_in[0];
    const float* targets = (const float*)d_in[1];
    // d_in[2]/d_in[3]: segments are contiguous, equal-size L=512 by construction.
    const int E = in_sizes[0];
    const int G = E / L;
    const int nblocks = (G + WPB - 1) / WPB;

    float* partials = (float*)d_ws;  // nblocks*4 floats, fully overwritten
    graph_loss_kernel<<<nblocks, BLK, 0, stream>>>(logits, targets, G, partials);
    finalize_kernel<<<1, BLK, 0, stream>>>(partials, nblocks, (float*)d_out);
}

// Round 4
// 83.770 us; speedup vs baseline: 4.2757x; 1.4635x over previous
//
#include <hip/hip_runtime.h>
#include <math.h>

#define L        512
#define BLK      256
#define WPB      4          // waves (graphs) per block
#define KTOP     32
#define NEGV     (-1e30f)

#define LOG2E    1.4426950408889634f
#define LOG2E10  14.426950408889634f   // (1/T=10) * log2(e)
#define LN2      0.6931471805599453f
#define M_L2E    0.7213475204444817f   // MARGIN(0.5) * log2(e)

#if __has_builtin(__builtin_amdgcn_exp2f)
#define EXP2F(x) __builtin_amdgcn_exp2f(x)
#else
#define EXP2F(x) exp2f(x)
#endif
#if __has_builtin(__builtin_amdgcn_logf)
#define LOG2F(x) __builtin_amdgcn_logf(x)
#else
#define LOG2F(x) __log2f(x)
#endif

// softplus(x)/ln2 with x2 = x*log2e:  max(x2,0) + log2(1 + 2^(-|x2|))
__device__ __forceinline__ float softplus_l2(float x2) {
    return fmaxf(x2, 0.0f) + LOG2F(1.0f + EXP2F(fminf(x2, -x2)));
}

__device__ __forceinline__ float waveSum(float v) {
#pragma unroll
    for (int off = 32; off; off >>= 1)
        v += __shfl_xor(v, off, 64);
    return v;
}

// # of set bits in m strictly below this lane
__device__ __forceinline__ unsigned lanes_below(unsigned long long m) {
    return __builtin_amdgcn_mbcnt_hi((unsigned)(m >> 32),
           __builtin_amdgcn_mbcnt_lo((unsigned)(m & 0xffffffffull), 0u));
}

__global__ __launch_bounds__(BLK) void graph_loss_kernel(
    const float* __restrict__ logits,
    const float* __restrict__ targets,
    int G,
    float* __restrict__ partials /* [gridDim.x*4] */)
{
    __shared__ float hard_s[WPB][KTOP];   // natural-units hard negatives
    __shared__ float pos_s[WPB][L];       // positives pre-scaled by log2e
    __shared__ float wres[WPB][4];

    const int tid  = threadIdx.x;
    const int lane = tid & 63;
    const int w    = tid >> 6;
    const int g    = blockIdx.x * WPB + w;
    const bool valid = (g < G);   // wave-uniform

    float lw = 0.0f, contrib = 0.0f;
    float has_pos_f = 0.0f, active_f = 0.0f;

    if (valid) {
        // Each lane owns elements [lane*8, lane*8+8): two float4 loads each.
        const float4* lg4 = (const float4*)(logits  + (size_t)g * L);
        const float4* tg4 = (const float4*)(targets + (size_t)g * L);
        const float4 la = lg4[lane * 2], lb = lg4[lane * 2 + 1];
        const float4 ta = tg4[lane * 2], tb = tg4[lane * 2 + 1];
        float v[8]  = {la.x, la.y, la.z, la.w, lb.x, lb.y, lb.z, lb.w};
        float tv[8] = {ta.x, ta.y, ta.z, ta.w, tb.x, tb.y, tb.z, tb.w};
        bool  p[8];
        unsigned nu[8];  // order-preserving uint key of negatives; 0 for positives

#pragma unroll
        for (int e = 0; e < 8; e++) {
            p[e] = tv[e] > 0.5f;
            const unsigned i = __float_as_uint(v[e]);
            const unsigned msk = (unsigned)((int)i >> 31) | 0x80000000u;
            nu[e] = p[e] ? 0u : (i ^ msk);
        }

        // ---- listwise LSEs in log2 domain: u = l * 10 * log2e ----
        float u[8];
        float s_mx = NEGV, p_mx = NEGV;
#pragma unroll
        for (int e = 0; e < 8; e++) {
            u[e] = v[e] * LOG2E10;
            s_mx = fmaxf(s_mx, u[e]);
            p_mx = fmaxf(p_mx, p[e] ? u[e] : NEGV);
        }
#pragma unroll
        for (int off = 32; off; off >>= 1) {
            s_mx = fmaxf(s_mx, __shfl_xor(s_mx, off, 64));
            p_mx = fmaxf(p_mx, __shfl_xor(p_mx, off, 64));
        }
        float se_all = 0.0f, se_pos = 0.0f;
#pragma unroll
        for (int e = 0; e < 8; e++) {
            se_all += EXP2F(u[e] - s_mx);
            const float ep = EXP2F(u[e] - p_mx);   // may be inf; masked below
            se_pos += p[e] ? ep : 0.0f;
        }
#pragma unroll
        for (int off = 32; off; off >>= 1) {
            se_all += __shfl_xor(se_all, off, 64);
            se_pos += __shfl_xor(se_pos, off, 64);
        }

        // ---- compact positives (pre-scaled by log2e) into LDS; get P ----
        int pbase = 0;
#pragma unroll
        for (int e = 0; e < 8; e++) {
            const unsigned long long m = __ballot((int)p[e]);
            if (p[e]) pos_s[w][pbase + lanes_below(m)] = v[e] * LOG2E;
            pbase += __popcll(m);
        }
        const int P = pbase;

        if (P > 0) {
            has_pos_f = 1.0f;
            lw = LN2 * ((s_mx + LOG2F(se_all)) - (p_mx + LOG2F(se_pos)));
        }
        const int neg_cnt = L - P;
        const int K = neg_cnt < KTOP ? neg_cnt : KTOP;
        const bool do_pair = (P > 0) && (K > 0);

        if (do_pair) {
            // ---- radix-select with early exit at exact count ----
            unsigned prefix = 0u;
            int exact = 0;
            for (int b = 31; b >= 0; --b) {
                const unsigned cand = prefix | (1u << b);
                int cnt = 0;
#pragma unroll
                for (int e = 0; e < 8; e++)
                    cnt += __popcll(__ballot(nu[e] >= cand));
                if (cnt >= K) {
                    prefix = cand;
                    if (cnt == K) { exact = 1; break; }
                }
            }
            // selection threshold: keys > lo (== ">= prefix" when exact)
            const unsigned lo = prefix - (unsigned)exact;
            // float value of the tie threshold (unused when exact: wt==0)
            const unsigned ti = prefix ^ ((prefix & 0x80000000u) ? 0x80000000u
                                                                 : 0xFFFFFFFFu);
            const float tval = __uint_as_float(ti);

            // ---- compact hard negatives (natural units), get c_gt ----
            int hbase = 0;
#pragma unroll
            for (int e = 0; e < 8; e++) {
                const bool gt = nu[e] > lo;
                const unsigned long long m = __ballot((int)gt);
                if (gt) hard_s[w][hbase + lanes_below(m)] = v[e];
                hbase += __popcll(m);
            }
            const int c_gt = hbase;

            // ---- pairwise: sum softplus over (hard x positives), log2 dom ----
            float psum2 = 0.0f;
            for (int n = 0; n < c_gt; n++) {
                const float c2 = fmaf(hard_s[w][n], LOG2E, M_L2E);
                for (int pp = lane; pp < P; pp += 64)
                    psum2 += softplus_l2(c2 - pos_s[w][pp]);
            }
            const float wt = (float)(K - c_gt);
            if (wt > 0.0f) {   // wave-uniform
                const float c2 = fmaf(tval, LOG2E, M_L2E);
                float tsum = 0.0f;
                for (int pp = lane; pp < P; pp += 64)
                    tsum += softplus_l2(c2 - pos_s[w][pp]);
                psum2 += wt * tsum;
            }
            const float psum = waveSum(psum2) * LN2;
            contrib  = psum / fmaxf((float)P * (float)K, 1.0f);
            active_f = 1.0f;
        }
    }

    if (lane == 0) {
        wres[w][0] = lw;
        wres[w][1] = has_pos_f;
        wres[w][2] = contrib;
        wres[w][3] = active_f;
    }
    __syncthreads();
    if (tid < 4) {
        partials[blockIdx.x * 4 + tid] =
            wres[0][tid] + wres[1][tid] + wres[2][tid] + wres[3][tid];
    }
}

__global__ __launch_bounds__(BLK) void finalize_kernel(
    const float* __restrict__ partials, int nblocks, float* __restrict__ out)
{
    float s0 = 0, s1 = 0, s2 = 0, s3 = 0;
    for (int i = threadIdx.x; i < nblocks; i += BLK) {
        const float4 p = ((const float4*)partials)[i];
        s0 += p.x; s1 += p.y; s2 += p.z; s3 += p.w;
    }
#pragma unroll
    for (int off = 32; off; off >>= 1) {
        s0 += __shfl_xor(s0, off, 64);
        s1 += __shfl_xor(s1, off, 64);
        s2 += __shfl_xor(s2, off, 64);
        s3 += __shfl_xor(s3, off, 64);
    }
    __shared__ float red[4][4];
    const int lane = threadIdx.x & 63, wid = threadIdx.x >> 6;
    if (lane == 0) { red[wid][0]=s0; red[wid][1]=s1; red[wid][2]=s2; red[wid][3]=s3; }
    __syncthreads();
    if (threadIdx.x == 0) {
        const float a0 = red[0][0]+red[1][0]+red[2][0]+red[3][0];
        const float a1 = red[0][1]+red[1][1]+red[2][1]+red[3][1];
        const float a2 = red[0][2]+red[1][2]+red[2][2]+red[3][2];
        const float a3 = red[0][3]+red[1][3]+red[2][3]+red[3][3];
        const float listwise = a0 / fmaxf(a1, 1.0f);
        const float pairwise = a2 / fmaxf(a3, 1.0f);
        out[0] = 1.0f * listwise + 0.5f * pairwise;
    }
}

extern "C" void kernel_launch(void* const* d_in, const int* in_sizes, int n_in,
                              void* d_out, int out_size, void* d_ws, size_t ws_size,
                              hipStream_t stream) {
    const float* logits  = (const float*)d_in[0];
    const float* targets = (const float*)d_in[1];
    // d_in[2]/d_in[3]: segments are contiguous, equal-size L=512 by construction.
    const int E = in_sizes[0];
    const int G = E / L;
    const int nblocks = (G + WPB - 1) / WPB;

    float* partials = (float*)d_ws;  // nblocks*4 floats, fully overwritten
    graph_loss_kernel<<<nblocks, BLK, 0, stream>>>(logits, targets, G, partials);
    finalize_kernel<<<1, BLK, 0, stream>>>(partials, nblocks, (float*)d_out);
}